// Round 3
// baseline (313.436 us; speedup 1.0000x reference)
//
#include <hip/hip_runtime.h>

#define B_ 8
#define L_ 2048
#define D_ 512
#define BI 64
#define BJ 32
#define JSPLIT 2
#define JHALF (L_ / JSPLIT)        // 1024
#define JITERS (JHALF / BJ)        // 32
#define KTILE (BJ * D_)            // 16384 f16 = 32 KB
#define VTILE (D_ * BJ)            // 16384 f16 = 32 KB
#define PSTRIDE 40
#define NROWS (B_ * L_)            // 16384

typedef __attribute__((ext_vector_type(4))) float  floatx4;
typedef __attribute__((ext_vector_type(8))) _Float16 halfx8;
typedef __attribute__((ext_vector_type(4))) int    intx4;

static __device__ __forceinline__ unsigned int f2h_bits(float x) {
  _Float16 h = (_Float16)x;
  return (unsigned int)__builtin_bit_cast(unsigned short, h);
}

static __device__ __forceinline__ void async_ld16(const unsigned short* g,
                                                  unsigned short* l) {
  __builtin_amdgcn_global_load_lds(
      (const __attribute__((address_space(1))) unsigned int*)g,
      (__attribute__((address_space(3))) unsigned int*)l, 16, 0, 0);
}

// ---------------------------------------------------------------------------
// prep: Kh[b][j][d-granules swizzled by j&7] = in*kw
//       Vt[b][d][jtile][j-granules swizzled by (d^(d>>2))&3] = in*vw
// grid (L/64, D/64, B), 256 threads. No serial b-loop (2048 blocks, 8/CU).
// ---------------------------------------------------------------------------
__global__ __launch_bounds__(256) void prep(const float* __restrict__ in,
                                            const float* __restrict__ kw,
                                            const float* __restrict__ vw,
                                            unsigned short* __restrict__ Kh,
                                            unsigned short* __restrict__ Vt) {
  const int lt = blockIdx.x * 64;
  const int dt = blockIdx.y * 64;
  const int b  = blockIdx.z;
  const int t  = threadIdx.x;
  __shared__ unsigned short vtile[64][66];

  #pragma unroll
  for (int i = 0; i < 4; ++i) {
    int c = i * 256 + t, r = c >> 4, c4 = (c & 15) * 4;
    int j = lt + r;
    size_t gi = ((size_t)b * L_ + j) * D_ + dt + c4;
    size_t wi = (size_t)j * D_ + dt + c4;
    float4 iv = *(const float4*)(in + gi);
    float4 kv = *(const float4*)(kw + wi);
    float4 vv = *(const float4*)(vw + wi);
    unsigned int p0 = f2h_bits(iv.x * kv.x) | (f2h_bits(iv.y * kv.y) << 16);
    unsigned int p1 = f2h_bits(iv.z * kv.z) | (f2h_bits(iv.w * kv.w) << 16);
    int gs = (((dt + c4) >> 3) ^ (j & 7));
    uint2 pk; pk.x = p0; pk.y = p1;
    *(uint2*)(Kh + ((size_t)b * L_ + j) * D_ + gs * 8 + (c4 & 7)) = pk;
    vtile[r][c4 + 0] = (unsigned short)f2h_bits(iv.x * vv.x);
    vtile[r][c4 + 1] = (unsigned short)f2h_bits(iv.y * vv.y);
    vtile[r][c4 + 2] = (unsigned short)f2h_bits(iv.z * vv.z);
    vtile[r][c4 + 3] = (unsigned short)f2h_bits(iv.w * vv.w);
  }
  __syncthreads();
  #pragma unroll
  for (int i = 0; i < 2; ++i) {
    int c = i * 256 + t, dd = c >> 3, l8 = (c & 7) * 8;
    int dg = dt + dd;
    int jglob = lt + l8;
    int ov[4];
    #pragma unroll
    for (int k2 = 0; k2 < 4; ++k2)
      ov[k2] = (int)((unsigned int)vtile[l8 + 2 * k2][dd] |
                     ((unsigned int)vtile[l8 + 2 * k2 + 1][dd] << 16));
    int gv  = (jglob & 31) >> 3;
    int key = (dg ^ (dg >> 2)) & 3;
    size_t idx = (((size_t)b * D_ + dg) * (L_ / BJ) + (jglob >> 5)) * BJ +
                 (size_t)((gv ^ key) * 8);
    intx4 o; o[0] = ov[0]; o[1] = ov[1]; o[2] = ov[2]; o[3] = ov[3];
    *(intx4*)(Vt + idx) = o;
  }
}

// ---------------------------------------------------------------------------
// flash (j-split partial): grid (L/BI, JSPLIT*B), 256 thr = 4 waves.
// 2 blocks/CU (LDS 69 KB, __launch_bounds__(256,2)). Single-buffer async
// staging, 2 barriers/iter; the other co-resident block hides the drains.
// Emits normalized partial O (f16) + (m,l) per row.
// ---------------------------------------------------------------------------
static __device__ __forceinline__ void stage_tiles(const unsigned short* Kg,
                                                   const unsigned short* Vg,
                                                   unsigned short* Kl,
                                                   unsigned short* Vl, int tid) {
  const int wb = tid & 192;  // wave base (uniform per wave)
  #pragma unroll
  for (int i = 0; i < 8; ++i) {
    int gl = i * 256 + tid;
    async_ld16(Kg + (size_t)gl * 8, Kl + (i * 256 + wb) * 8);
  }
  #pragma unroll
  for (int i = 0; i < 8; ++i) {
    int gl = i * 256 + tid;
    int d = gl >> 2, g8 = gl & 3;
    async_ld16(Vg + (size_t)d * L_ + g8 * 8, Vl + (i * 256 + wb) * 8);
  }
}

__global__ __launch_bounds__(256, 2) void flash(const float* __restrict__ in,
                                                const float* __restrict__ qw,
                                                const unsigned short* __restrict__ Kh,
                                                const unsigned short* __restrict__ Vt,
                                                _Float16* __restrict__ Oh,
                                                float2* __restrict__ ml) {
  const int b    = blockIdx.y >> 1;
  const int g    = blockIdx.y & 1;       // j-half
  const int i0   = blockIdx.x * BI;
  const int tid  = threadIdx.x;
  const int w    = tid >> 6;
  const int lane = tid & 63;
  const int ln16 = lane & 15;
  const int quad = lane >> 4;

  __shared__ unsigned short Ksh[KTILE];          // 32 KB
  __shared__ unsigned short Vsh[VTILE];          // 32 KB
  __shared__ unsigned short Psh[BI * PSTRIDE];   //  5 KB

  const float kScale = 0.51012599f;  // log2(e)/sqrt(8): exp2-domain softmax

  // ---- Q fragments in registers (A-layout: m=ln16, k=quad*8+t) ----
  halfx8 qf[16];
  {
    const int qi = i0 + w * 16 + ln16;
    const float* ip = in + ((size_t)b * L_ + qi) * D_;
    const float* wp = qw + (size_t)qi * D_;
    #pragma unroll
    for (int ks = 0; ks < 16; ++ks) {
      int d0 = ks * 32 + quad * 8;
      float4 a0 = *(const float4*)(ip + d0);
      float4 a1 = *(const float4*)(ip + d0 + 4);
      float4 w0 = *(const float4*)(wp + d0);
      float4 w1 = *(const float4*)(wp + d0 + 4);
      halfx8 q;
      q[0] = (_Float16)(a0.x * w0.x * kScale);
      q[1] = (_Float16)(a0.y * w0.y * kScale);
      q[2] = (_Float16)(a0.z * w0.z * kScale);
      q[3] = (_Float16)(a0.w * w0.w * kScale);
      q[4] = (_Float16)(a1.x * w1.x * kScale);
      q[5] = (_Float16)(a1.y * w1.y * kScale);
      q[6] = (_Float16)(a1.z * w1.z * kScale);
      q[7] = (_Float16)(a1.w * w1.w * kScale);
      qf[ks] = q;
    }
  }

  float m_r[4], l_r[4];
  #pragma unroll
  for (int r = 0; r < 4; ++r) { m_r[r] = -1e30f; l_r[r] = 0.f; }
  floatx4 O[32];
  #pragma unroll
  for (int ct = 0; ct < 32; ++ct) O[ct] = (floatx4){0.f, 0.f, 0.f, 0.f};

  const unsigned short* KgB = Kh + ((size_t)b * L_ + g * JHALF) * D_;
  const unsigned short* VgB = Vt + (size_t)b * D_ * L_ + (size_t)g * JHALF;
  const int xk = ln16 & 7;
  const int xv = (ln16 ^ (ln16 >> 2)) & 3;

  for (int jb = 0; jb < JITERS; ++jb) {
    stage_tiles(KgB + (size_t)jb * KTILE, VgB + jb * BJ, Ksh, Vsh, tid);
    __syncthreads();  // drain vmcnt(0): this tile's staged loads complete

    // ---- S = Q K^T, 4 independent MFMA chains ----
    floatx4 acc[2][2];
    #pragma unroll
    for (int jt = 0; jt < 2; ++jt) {
      acc[jt][0] = (floatx4){0.f, 0.f, 0.f, 0.f};
      acc[jt][1] = (floatx4){0.f, 0.f, 0.f, 0.f};
      const unsigned short* kr = Ksh + (size_t)(jt * 16 + ln16) * D_;
      #pragma unroll
      for (int ks = 0; ks < 16; ++ks) {
        halfx8 bk = *(const halfx8*)(kr + (((4 * ks + quad) ^ xk) * 8));
        acc[jt][ks & 1] =
            __builtin_amdgcn_mfma_f32_16x16x32_f16(qf[ks], bk, acc[jt][ks & 1], 0, 0, 0);
      }
    }
    floatx4 sA[2];
    sA[0] = acc[0][0] + acc[0][1];
    sA[1] = acc[1][0] + acc[1][1];

    // ---- online softmax ----
    float mt[4];
    #pragma unroll
    for (int r = 0; r < 4; ++r) mt[r] = fmaxf(sA[0][r], sA[1][r]);
    #pragma unroll
    for (int off = 1; off < 16; off <<= 1) {
      #pragma unroll
      for (int r = 0; r < 4; ++r) mt[r] = fmaxf(mt[r], __shfl_xor(mt[r], off));
    }
    float al[4], ts[4];
    bool upd = false;
    #pragma unroll
    for (int r = 0; r < 4; ++r) {
      float mn = fmaxf(m_r[r], mt[r]);
      al[r] = exp2f(m_r[r] - mn);
      upd = upd || (mn != m_r[r]);
      m_r[r] = mn;
      float e0 = exp2f(sA[0][r] - mn);
      float e1 = exp2f(sA[1][r] - mn);
      sA[0][r] = e0; sA[1][r] = e1;
      ts[r] = e0 + e1;
    }
    #pragma unroll
    for (int off = 1; off < 16; off <<= 1) {
      #pragma unroll
      for (int r = 0; r < 4; ++r) ts[r] += __shfl_xor(ts[r], off);
    }
    #pragma unroll
    for (int r = 0; r < 4; ++r) l_r[r] = l_r[r] * al[r] + ts[r];

    if (__any((int)upd)) {
      #pragma unroll
      for (int ct = 0; ct < 32; ++ct) {
        #pragma unroll
        for (int r = 0; r < 4; ++r) O[ct][r] *= al[r];
      }
    }

    // ---- P: C-layout regs -> A-layout via LDS (same wave, no barrier) ----
    #pragma unroll
    for (int jt = 0; jt < 2; ++jt) {
      #pragma unroll
      for (int r = 0; r < 4; ++r)
        Psh[(w * 16 + quad * 4 + r) * PSTRIDE + jt * 16 + ln16] =
            (unsigned short)f2h_bits(sA[jt][r]);
    }
    halfx8 pf = *(const halfx8*)(&Psh[(w * 16 + ln16) * PSTRIDE + quad * 8]);

    // ---- O += P V ----
    const unsigned short* vb = Vsh + ln16 * BJ + ((quad ^ xv) * 8);
    #pragma unroll
    for (int ct = 0; ct < 32; ++ct) {
      halfx8 vf = *(const halfx8*)(vb + ct * 16 * BJ);
      O[ct] = __builtin_amdgcn_mfma_f32_16x16x32_f16(pf, vf, O[ct], 0, 0, 0);
    }
    __syncthreads();  // all LDS reads done before next stage overwrites
  }

  // ---- partial epilogue: Oh = O/l (f16), ml = (m, l) ----
  float inv[4];
  #pragma unroll
  for (int r = 0; r < 4; ++r) inv[r] = 1.0f / l_r[r];
  const size_t rowbase = (size_t)g * NROWS + (size_t)b * L_ + i0 + w * 16;
  _Float16* op = Oh + rowbase * D_;
  #pragma unroll
  for (int r = 0; r < 4; ++r) {
    int row = quad * 4 + r;
    #pragma unroll
    for (int ct = 0; ct < 32; ++ct)
      op[(size_t)row * D_ + ct * 16 + ln16] = (_Float16)(O[ct][r] * inv[r]);
  }
  if (ln16 == 0) {
    #pragma unroll
    for (int r = 0; r < 4; ++r) {
      float2 v; v.x = m_r[r]; v.y = l_r[r];
      ml[rowbase + quad * 4 + r] = v;
    }
  }
}

// ---------------------------------------------------------------------------
// combine: out = (a1*O1 + a2*O2)/(a1+a2), a_g = exp2(m_g - M) * l_g
// grid NROWS/4 blocks, 256 threads (4 rows/block, 64 lanes x 8 d each).
// ---------------------------------------------------------------------------
__global__ __launch_bounds__(256) void combine(const _Float16* __restrict__ Oh,
                                               const float2* __restrict__ ml,
                                               float* __restrict__ out) {
  const int row = blockIdx.x * 4 + (threadIdx.x >> 6);
  const int d0  = (threadIdx.x & 63) * 8;
  float2 m1 = ml[row];
  float2 m2 = ml[NROWS + row];
  float M  = fmaxf(m1.x, m2.x);
  float a1 = exp2f(m1.x - M) * m1.y;
  float a2 = exp2f(m2.x - M) * m2.y;
  float inv = 1.0f / (a1 + a2);
  float w1 = a1 * inv, w2 = a2 * inv;
  halfx8 o1 = *(const halfx8*)(Oh + (size_t)row * D_ + d0);
  halfx8 o2 = *(const halfx8*)(Oh + ((size_t)NROWS + row) * D_ + d0);
  float4 r0, r1;
  r0.x = w1 * (float)o1[0] + w2 * (float)o2[0];
  r0.y = w1 * (float)o1[1] + w2 * (float)o2[1];
  r0.z = w1 * (float)o1[2] + w2 * (float)o2[2];
  r0.w = w1 * (float)o1[3] + w2 * (float)o2[3];
  r1.x = w1 * (float)o1[4] + w2 * (float)o2[4];
  r1.y = w1 * (float)o1[5] + w2 * (float)o2[5];
  r1.z = w1 * (float)o1[6] + w2 * (float)o2[6];
  r1.w = w1 * (float)o1[7] + w2 * (float)o2[7];
  *(float4*)(out + (size_t)row * D_ + d0)     = r0;
  *(float4*)(out + (size_t)row * D_ + d0 + 4) = r1;
}

// ---------------------------------------------------------------------------
extern "C" void kernel_launch(void* const* d_in, const int* in_sizes, int n_in,
                              void* d_out, int out_size, void* d_ws, size_t ws_size,
                              hipStream_t stream) {
  const float* in = (const float*)d_in[0];
  const float* qw = (const float*)d_in[1];
  const float* kw = (const float*)d_in[2];
  const float* vw = (const float*)d_in[3];
  float* out = (float*)d_out;

  unsigned short* Kh = (unsigned short*)d_ws;                 // 16.78 MB
  unsigned short* Vt = Kh + (size_t)B_ * L_ * D_;             // 16.78 MB
  _Float16* Oh = (_Float16*)(Vt + (size_t)B_ * L_ * D_);      // 33.55 MB
  float2* ml = (float2*)(Oh + (size_t)JSPLIT * NROWS * D_);   //  0.26 MB

  prep<<<dim3(L_ / 64, D_ / 64, B_), dim3(256), 0, stream>>>(in, kw, vw, Kh, Vt);
  flash<<<dim3(L_ / BI, JSPLIT * B_), dim3(256), 0, stream>>>(in, qw, Kh, Vt, Oh, ml);
  combine<<<dim3(NROWS / 4), dim3(256), 0, stream>>>(Oh, ml, out);
}